// Round 7
// baseline (46.606 us; speedup 1.0000x reference)
//
#include <hip/hip_runtime.h>
#include <math.h>
#include <climits>

#define BLOCK 256
#define NCHUNK 5
#define LDSN (NCHUNK * BLOCK * 4)       // 5120 staged f32 per array per block
#define LARGE_NEG (-1.0e9f)
#define SCORE_EPS 1e-6f
#define RANDP 0.1f
#define PROB_EPS 1e-12f
#define F32EPS 1.1920928955078125e-7f   // torch.finfo(float32).eps

// async global->LDS DMA: 16B per lane, LDS dest = wave-uniform base + lane*16
__device__ __forceinline__ void stage16(const void* g, void* l) {
  __builtin_amdgcn_global_load_lds(
      (const __attribute__((address_space(1))) void*)g,
      (__attribute__((address_space(3))) void*)l, 16, 0, 0);
}

// ---------- kernel 1: fused setup (round-5 version, restored) --------------
// Blocks [0, nbPtr): segment pointers via binary search (edge_batch sorted).
// Block nbPtr: valid_edges storage-format detect on an 8 KB sample.
//   byte-bool (~90% nonzero bytes) vs int32 0/1 (~22.5%) vs f32 0/1 (~45%).
__global__ void gfn_setup(const int* __restrict__ batch, int E, int G,
                          int* __restrict__ ptr,
                          const unsigned int* __restrict__ vwords, int nwords,
                          int nbytes, int* __restrict__ flag, int nbPtr) {
  if ((int)blockIdx.x < nbPtr) {
    int g = blockIdx.x * BLOCK + threadIdx.x;
    if (g > G) return;
    int lo = 0, hi = E;
    while (lo < hi) {
      int mid = (lo + hi) >> 1;
      if (batch[mid] < g) lo = mid + 1; else hi = mid;
    }
    ptr[g] = lo;   // first edge with batch >= g; segment g = [ptr[g], ptr[g+1])
  } else {
    int c = 0;
    for (int i = threadIdx.x; i < nwords; i += BLOCK) {
      unsigned int w = vwords[i];
      c += ((w & 0x000000FFu) != 0) + ((w & 0x0000FF00u) != 0) +
           ((w & 0x00FF0000u) != 0) + ((w & 0xFF000000u) != 0);
    }
#pragma unroll
    for (int o = 32; o >= 1; o >>= 1) c += __shfl_xor(c, o);
    __shared__ int part[4];
    if ((threadIdx.x & 63) == 0) part[threadIdx.x >> 6] = c;
    __syncthreads();
    if (threadIdx.x == 0) {
      int t = part[0] + part[1] + part[2] + part[3];
      flag[0] = (2 * t > nbytes) ? 1 : 0;
    }
  }
}

// ---------- kernel 2: one workgroup per graph, async-LDS-staged pipeline ---
// Stage: 20+20 global_load_lds calls (scores+resid), zero VGPR cost -> deep
//        MLP (~10 KB in flight per wave). One vmcnt(0)+barrier.
// AB: t = log(w)+r from LDS; fused 4-tuple reduce (smax, ssum, vc, tmax).
//     exp(log w - mj1) == w/M with M = max(smax,1);
//     max((log w - ld1) + r) == max(log w + r) - ld1.
// C : register-only exp-sum for stage-2 denominator.
// D : writes + argmax by t (monotone equivalence to reference).
__global__ __launch_bounds__(BLOCK, 4) void
gfn_main(const float* __restrict__ scores,
         const float* __restrict__ resid,
         const float* __restrict__ stop_resid,
         const void* __restrict__ validp,
         const int* __restrict__ ptr,
         const int* __restrict__ flag,
         float* __restrict__ out, int E, int G) {
  __shared__ float sS[LDSN];             // scores window; aliased as reduce
  __shared__ float sR[LDSN];             //   scratch after AB reads complete
  float* const redf = sS;                // sS[0..15]
  int* const redi = (int*)(sS + 16);     // sS[16..19]

  const int g = blockIdx.x;
  const int start = ptr[g];
  const int end = ptr[g + 1];
  const bool byteFmt = (flag[0] != 0);
  const unsigned char* vb = (const unsigned char*)validp;
  const int* vi = (const int*)validp;
  const int abase = start & ~3;          // 16B-aligned segment base
  const int wid = (int)(threadIdx.x >> 6);
  const int lane = (int)(threadIdx.x & 63);

  if ((E & 3) == 0 && (end - abase) <= LDSN) {
    // =================== fast path =========================================
    const int t4 = (int)threadIdx.x * 4;

    // ---- async stage: each wave issues 5+5 LDS-DMA calls back-to-back -----
    for (int ci = wid; ci < 4 * NCHUNK; ci += 4) {
      const int base = ci * 256;          // 256 f32 = 1 KB per wave-call
      const int gidx = abase + base + lane * 4;
      if (gidx < end) {                   // gidx%4==0 & E%4==0 -> gidx+3 < E
        stage16(scores + gidx, &sS[base]);
        stage16(resid + gidx, &sR[base]);
      }
    }

    // ---- valid -> per-thread 4-bit masks (normal loads, same drain) -------
    unsigned int vm[NCHUNK];
#pragma unroll
    for (int j = 0; j < NCHUNK; ++j) {
      const int e0 = abase + j * 1024 + t4;
      vm[j] = 0u;
      if (e0 < end) {
        if (byteFmt) {
          const unsigned int u = *(const unsigned int*)(vb + e0);
          vm[j] = ((u & 0x000000FFu) ? 1u : 0u) | ((u & 0x0000FF00u) ? 2u : 0u) |
                  ((u & 0x00FF0000u) ? 4u : 0u) | ((u & 0xFF000000u) ? 8u : 0u);
        } else {
          const int4 u = *(const int4*)(vi + e0);
          vm[j] = (u.x ? 1u : 0u) | (u.y ? 2u : 0u) |
                  (u.z ? 4u : 0u) | (u.w ? 8u : 0u);
        }
      }
    }

    asm volatile("s_waitcnt vmcnt(0)" ::: "memory");
    __syncthreads();

    // ---- phase AB: t = log(w)+r; fused 4-tuple reduce ---------------------
    float c[NCHUNK][4];                  // t (or LARGE_NEG)
    float smax = 0.f, ssum = 0.f, vc = 0.f, tmax = LARGE_NEG;
#pragma unroll
    for (int j = 0; j < NCHUNK; ++j) {
      const int e0 = abase + j * 1024 + t4;
      if (e0 < end) {
        const float4 s4 = *(const float4*)&sS[j * 1024 + t4];
        const float4 r4 = *(const float4*)&sR[j * 1024 + t4];
        const float ss[4] = {s4.x, s4.y, s4.z, s4.w};
        const float rr[4] = {r4.x, r4.y, r4.z, r4.w};
#pragma unroll
        for (int k = 0; k < 4; ++k) {
          const int e = e0 + k;
          const bool ok = ((vm[j] >> k) & 1u) && (e >= start) && (e < end);
          const float w = ok ? fmaxf(ss[k], SCORE_EPS) : 0.f;
          smax = fmaxf(smax, w);
          ssum += w;
          vc += ok ? 1.f : 0.f;
          const float t = ok ? (__logf(w) + rr[k]) : LARGE_NEG;
          c[j][k] = t;
          tmax = fmaxf(tmax, t);
        }
      } else {
#pragma unroll
        for (int k = 0; k < 4; ++k) c[j][k] = LARGE_NEG;
      }
    }
    __syncthreads();                     // sS/sR reads done -> redf alias safe
#pragma unroll
    for (int o = 32; o >= 1; o >>= 1) {
      smax = fmaxf(smax, __shfl_xor(smax, o));
      ssum += __shfl_xor(ssum, o);
      vc += __shfl_xor(vc, o);
      tmax = fmaxf(tmax, __shfl_xor(tmax, o));
    }
    if (lane == 0) {
      redf[wid] = smax; redf[4 + wid] = ssum; redf[8 + wid] = vc;
      redf[12 + wid] = tmax;
    }
    __syncthreads();
    smax = fmaxf(fmaxf(redf[0], redf[1]), fmaxf(redf[2], redf[3]));
    ssum = (redf[4] + redf[5]) + (redf[6] + redf[7]);
    vc = (redf[8] + redf[9]) + (redf[10] + redf[11]);
    tmax = fmaxf(fmaxf(redf[12], redf[13]), fmaxf(redf[14], redf[15]));
    __syncthreads();

    // ---- scalar stage-1/2 plumbing ----------------------------------------
    const float M = fmaxf(smax, 1.f);
    const float invM = 1.f / M;
    const float ld1 = __logf(M) + __logf(ssum * invM + invM + F32EPS);
    const float m2 = tmax - ld1;             // max combined edge logit
    const float ss2 = stop_resid[g] - ld1;   // combined stop logit
    const float mj2 = fmaxf(m2, ss2);
    const float off2 = ld1 + mj2;            // exp(c - mj2) = exp(t - off2)

    // ---- phase C (regs only): stage-2 denominator -------------------------
    float s2 = 0.f;
#pragma unroll
    for (int j = 0; j < NCHUNK; ++j)
#pragma unroll
      for (int k = 0; k < 4; ++k) s2 += __expf(c[j][k] - off2);  // inert -> 0
#pragma unroll
    for (int o = 32; o >= 1; o >>= 1) s2 += __shfl_xor(s2, o);
    if (lane == 0) redf[wid] = s2;
    __syncthreads();
    s2 = (redf[0] + redf[1]) + (redf[2] + redf[3]);
    __syncthreads();
    const float ld2 = mj2 + __logf(s2 + __expf(ss2 - mj2) + F32EPS);
    const float clean_stop = ss2 - ld2;
    const float invt = 1.f / fmaxf(vc + 1.f, 1.f);
    const float off3 = ld1 + ld2;            // clean = t - off3

    // ---- phase D: writes; argmax by t (monotone => matches reference) -----
    float bv = -INFINITY;
    int bi = INT_MAX;
#pragma unroll
    for (int j = 0; j < NCHUNK; ++j) {
      const int e0 = abase + j * 1024 + t4;
      if (e0 < end) {
        float ov[4];
#pragma unroll
        for (int k = 0; k < 4; ++k) {
          const int e = e0 + k;
          const float t = c[j][k];
          const bool v = (t != LARGE_NEG);
          ov[k] = v ? (t - off3) : LARGE_NEG;
          if (v && (t > bv || (t == bv && e < bi))) { bv = t; bi = e; }
        }
        if (e0 >= start && e0 + 4 <= end) {
          *(float4*)(out + e0) = make_float4(ov[0], ov[1], ov[2], ov[3]);
        } else {
#pragma unroll
          for (int k = 0; k < 4; ++k) {
            const int e = e0 + k;
            if (e >= start && e < end) out[e] = ov[k];
          }
        }
      }
    }
#pragma unroll
    for (int o = 32; o >= 1; o >>= 1) {
      const float v2 = __shfl_xor(bv, o);
      const int i2 = __shfl_xor(bi, o);
      if (v2 > bv || (v2 == bv && i2 < bi)) { bv = v2; bi = i2; }
    }
    if (lane == 0) { redf[wid] = bv; redi[wid] = bi; }
    __syncthreads();
    if (threadIdx.x == 0) {
      bv = redf[0]; bi = redi[0];
      for (int w = 1; w < 4; ++w) {
        if (redf[w] > bv || (redf[w] == bv && redi[w] < bi)) {
          bv = redf[w]; bi = redi[w];
        }
      }
      const bool anyvalid = (bi != INT_MAX);
      const float wclean = bv - off3;      // winner's clean_log_edge
      float bvls = LARGE_NEG;              // best log_sample_edge (ref formula)
      if (anyvalid) {
        const float p = (1.f - RANDP) * __expf(wclean) + RANDP * invt;
        bvls = __logf(fmaxf(p, PROB_EPS));
      }
      const float ssp = (1.f - RANDP) * __expf(clean_stop) + RANDP * invt;
      const float lss = __logf(fmaxf(ssp, PROB_EPS));
      const bool take_stop = (lss >= bvls);
      out[E + g]         = clean_stop;                         // output 1
      out[E + G + g]     = take_stop ? (float)end : (float)bi; // output 2
      out[E + 2 * G + g] = take_stop ? clean_stop : wclean;    // output 3
    }
    return;
  }

  // =================== fallback: 5-pass global reread (n > LDSN) ===========
  const int n = end - start;
  auto load_l = [&](int e) -> float {
    float s = scores[e];
    int v = byteFmt ? (int)vb[e] : vi[e];
    return v ? __logf(fmaxf(s, SCORE_EPS)) : LARGE_NEG;
  };

  float m1 = LARGE_NEG, vc = 0.f;
  for (int i = threadIdx.x; i < n; i += BLOCK) {
    float l = load_l(start + i);
    m1 = fmaxf(m1, l);
    if (l != LARGE_NEG) vc += 1.f;
  }
#pragma unroll
  for (int o = 32; o >= 1; o >>= 1) {
    m1 = fmaxf(m1, __shfl_xor(m1, o));
    vc += __shfl_xor(vc, o);
  }
  if (lane == 0) { redf[wid] = m1; redf[4 + wid] = vc; }
  __syncthreads();
  m1 = fmaxf(fmaxf(redf[0], redf[1]), fmaxf(redf[2], redf[3]));
  vc = (redf[4] + redf[5]) + (redf[6] + redf[7]);
  __syncthreads();

  const float mj1 = fmaxf(m1, 0.f);
  float s1 = 0.f;
  for (int i = threadIdx.x; i < n; i += BLOCK)
    s1 += __expf(load_l(start + i) - mj1);
#pragma unroll
  for (int o = 32; o >= 1; o >>= 1) s1 += __shfl_xor(s1, o);
  if (lane == 0) redf[wid] = s1;
  __syncthreads();
  s1 = (redf[0] + redf[1]) + (redf[2] + redf[3]);
  __syncthreads();
  const float ld1 = mj1 + __logf(s1 + __expf(-mj1) + F32EPS);

  float m2 = LARGE_NEG;
  for (int i = threadIdx.x; i < n; i += BLOCK) {
    float l = load_l(start + i);
    float cc = (l != LARGE_NEG) ? (l - ld1 + resid[start + i]) : LARGE_NEG;
    m2 = fmaxf(m2, cc);
  }
#pragma unroll
  for (int o = 32; o >= 1; o >>= 1) m2 = fmaxf(m2, __shfl_xor(m2, o));
  if (lane == 0) redf[wid] = m2;
  __syncthreads();
  m2 = fmaxf(fmaxf(redf[0], redf[1]), fmaxf(redf[2], redf[3]));
  __syncthreads();

  const float ss2 = stop_resid[g] - ld1;
  const float mj2 = fmaxf(m2, ss2);
  float s2 = 0.f;
  for (int i = threadIdx.x; i < n; i += BLOCK) {
    float l = load_l(start + i);
    float cc = (l != LARGE_NEG) ? (l - ld1 + resid[start + i]) : LARGE_NEG;
    s2 += __expf(cc - mj2);
  }
#pragma unroll
  for (int o = 32; o >= 1; o >>= 1) s2 += __shfl_xor(s2, o);
  if (lane == 0) redf[wid] = s2;
  __syncthreads();
  s2 = (redf[0] + redf[1]) + (redf[2] + redf[3]);
  __syncthreads();
  const float ld2 = mj2 + __logf(s2 + __expf(ss2 - mj2) + F32EPS);
  const float clean_stop = ss2 - ld2;
  const float invt = 1.f / fmaxf(vc + 1.f, 1.f);

  float bv = -INFINITY; int bi = INT_MAX; float bc = 0.f;
  for (int i = threadIdx.x; i < n; i += BLOCK) {
    const int e = start + i;
    float l = load_l(e);
    float cc = (l != LARGE_NEG) ? (l - ld1 + resid[e]) : LARGE_NEG;
    const bool v = (cc != LARGE_NEG);
    const float clean = cc - ld2;
    out[e] = v ? clean : LARGE_NEG;
    float ls;
    if (v) {
      const float p = (1.f - RANDP) * __expf(clean) + RANDP * invt;
      ls = __logf(fmaxf(p, PROB_EPS));
    } else ls = LARGE_NEG;
    if (ls > bv || (ls == bv && e < bi)) { bv = ls; bi = e; bc = clean; }
  }
#pragma unroll
  for (int o = 32; o >= 1; o >>= 1) {
    const float v2 = __shfl_xor(bv, o);
    const int i2 = __shfl_xor(bi, o);
    const float c2 = __shfl_xor(bc, o);
    if (v2 > bv || (v2 == bv && i2 < bi)) { bv = v2; bi = i2; bc = c2; }
  }
  if (lane == 0) { redf[wid] = bv; redf[4 + wid] = bc; redi[wid] = bi; }
  __syncthreads();
  if (threadIdx.x == 0) {
    bv = redf[0]; bi = redi[0]; bc = redf[4];
    for (int w = 1; w < 4; ++w) {
      if (redf[w] > bv || (redf[w] == bv && redi[w] < bi)) {
        bv = redf[w]; bi = redi[w]; bc = redf[4 + w];
      }
    }
    const float ssp = (1.f - RANDP) * __expf(clean_stop) + RANDP * invt;
    const float lss = __logf(fmaxf(ssp, PROB_EPS));
    const bool take_stop = (lss >= bv);
    out[E + g]         = clean_stop;
    out[E + G + g]     = take_stop ? (float)end : (float)bi;
    out[E + 2 * G + g] = take_stop ? clean_stop : bc;
  }
}

extern "C" void kernel_launch(void* const* d_in, const int* in_sizes, int n_in,
                              void* d_out, int out_size, void* d_ws, size_t ws_size,
                              hipStream_t stream) {
  const float* scores     = (const float*)d_in[0];
  const float* resid      = (const float*)d_in[1];
  const float* stop_resid = (const float*)d_in[2];
  const void*  validp     = d_in[3];
  const int*   batch      = (const int*)d_in[4];
  const int E = in_sizes[0];
  const int G = in_sizes[2];

  int* flag = (int*)d_ws;            // ws[0]: valid_edges format flag
  int* ptr  = (int*)d_ws + 64;       // ws[64..64+G+1): segment pointers
  float* out = (float*)d_out;

  int sample_bytes = (E < 8192) ? (E & ~3) : 8192;
  int nbPtr = (G + 1 + BLOCK - 1) / BLOCK;
  gfn_setup<<<nbPtr + 1, BLOCK, 0, stream>>>(batch, E, G, ptr,
                                             (const unsigned int*)validp,
                                             sample_bytes / 4, sample_bytes,
                                             flag, nbPtr);
  gfn_main<<<G, BLOCK, 0, stream>>>(scores, resid, stop_resid, validp, ptr,
                                    flag, out, E, G);
}

// Round 8
// 41.914 us; speedup vs baseline: 1.1119x; 1.1119x over previous
//
#include <hip/hip_runtime.h>
#include <math.h>
#include <climits>

#define BLOCK 256
#define NCHUNK 5
#define LDSN (NCHUNK * 1024)            // 5120 staged f32 per array per block
#define LARGE_NEG (-1.0e9f)
#define SCORE_EPS 1e-6f
#define RANDP 0.1f
#define PROB_EPS 1e-12f
#define F32EPS 1.1920928955078125e-7f   // torch.finfo(float32).eps

// async global->LDS DMA: 16B per lane, LDS dest = wave-uniform base + lane*16
__device__ __forceinline__ void stage16(const void* g, void* l) {
  __builtin_amdgcn_global_load_lds(
      (const __attribute__((address_space(1))) void*)g,
      (__attribute__((address_space(3))) void*)l, 16, 0, 0);
}

#define WAITV(n) asm volatile("s_waitcnt vmcnt(" #n ")" ::: "memory")

// ---------- kernel 1: fused setup ------------------------------------------
// Blocks [0, nbPtr): ptr via windowed binary search (edge_batch sorted;
//   window g*E/G +/- 16384 > 11 sigma for multinomial data; VERIFIED, with
//   full-range fallback so correctness never depends on the distribution).
// Block nbPtr: valid_edges storage-format detect on an 8 KB sample.
__global__ void gfn_setup(const int* __restrict__ batch, int E, int G,
                          int* __restrict__ ptr,
                          const unsigned int* __restrict__ vwords, int nwords,
                          int nbytes, int* __restrict__ flag, int nbPtr) {
  if ((int)blockIdx.x < nbPtr) {
    int g = blockIdx.x * BLOCK + threadIdx.x;
    if (g > G) return;
    long long ghat = (long long)g * (long long)E / (long long)(G > 0 ? G : 1);
    long long wlo = ghat - 16384, whi = ghat + 16384;
    int lo = wlo > 0 ? (int)wlo : 0;
    int hi = whi < (long long)E ? (int)whi : E;
    while (lo < hi) {
      int mid = (lo + hi) >> 1;
      if (batch[mid] < g) lo = mid + 1; else hi = mid;
    }
    int r = lo;
    bool ok = (r == 0 || batch[r - 1] < g) && (r == E || batch[r] >= g);
    if (!ok) {                          // window missed: full-range redo
      lo = 0; hi = E;
      while (lo < hi) {
        int mid = (lo + hi) >> 1;
        if (batch[mid] < g) lo = mid + 1; else hi = mid;
      }
      r = lo;
    }
    ptr[g] = r;   // first edge with batch >= g; segment g = [ptr[g], ptr[g+1])
  } else {
    int c = 0;
    for (int i = threadIdx.x; i < nwords; i += BLOCK) {
      unsigned int w = vwords[i];
      c += ((w & 0x000000FFu) != 0) + ((w & 0x0000FF00u) != 0) +
           ((w & 0x00FF0000u) != 0) + ((w & 0xFF000000u) != 0);
    }
#pragma unroll
    for (int o = 32; o >= 1; o >>= 1) c += __shfl_xor(c, o);
    __shared__ int part[4];
    if ((threadIdx.x & 63) == 0) part[threadIdx.x >> 6] = c;
    __syncthreads();
    if (threadIdx.x == 0) {
      int t = part[0] + part[1] + part[2] + part[3];
      flag[0] = (2 * t > nbytes) ? 1 : 0;
    }
  }
}

// ---------- kernel 2: chunk-pipelined, one workgroup per graph -------------
// Per wave: issue 5 valid loads + 10 DMA (S_j,R_j for own sub-chunk 4j+wid),
// then consume chunk j under counted s_waitcnt vmcnt(8-2j) — compute rides
// inside the HBM stream instead of after it. Each wave reads only LDS it
// staged itself, so no barrier until the block reduce.
__global__ __launch_bounds__(BLOCK, 4) void
gfn_main(const float* __restrict__ scores,
         const float* __restrict__ resid,
         const float* __restrict__ stop_resid,
         const void* __restrict__ validp,
         const int* __restrict__ ptr,
         const int* __restrict__ flag,
         float* __restrict__ out, int E, int G) {
  __shared__ float sS[LDSN];             // scores window (reduce scratch alias)
  __shared__ float sR[LDSN];
  float* const redf = sS;                // reduce1: sS[0..15]
  float* const redf2 = sS + 16;          // reduce2: s2 sS[16..19], bv sS[20..23]
  int* const redi2 = (int*)(sS + 24);    //          bi sS[24..27]
  int* const redi = (int*)(sS + 16);     // fallback argmax idx slots

  const int g = blockIdx.x;
  const int start = ptr[g];
  const int end = ptr[g + 1];
  const bool byteFmt = (flag[0] != 0);
  const unsigned char* vb = (const unsigned char*)validp;
  const int* vi = (const int*)validp;
  const int abase = start & ~3;          // 16B-aligned segment base
  const int wid = (int)(threadIdx.x >> 6);
  const int lane = (int)(threadIdx.x & 63);

  if ((E & 3) == 0 && E >= 4 && (end - abase) <= LDSN) {
    // =================== fast path =========================================
    const int t4 = (int)threadIdx.x * 4;
    const int Ecap = E - 4;              // clamp: always-issue, deterministic

    // ---- valid loads first (vmcnt positions 0..4) -------------------------
    unsigned int vw[NCHUNK];
    int4 vq[NCHUNK];
    if (byteFmt) {
#pragma unroll
      for (int j = 0; j < NCHUNK; ++j) {
        int e0 = abase + j * 1024 + t4; e0 = e0 < Ecap ? e0 : Ecap;
        vw[j] = *(const unsigned int*)(vb + e0);
      }
    } else {
#pragma unroll
      for (int j = 0; j < NCHUNK; ++j) {
        int e0 = abase + j * 1024 + t4; e0 = e0 < Ecap ? e0 : Ecap;
        vq[j] = *(const int4*)(vi + e0);
      }
    }

    // ---- DMA issues (positions 5..14): S_j,R_j for own sub-chunk ----------
#pragma unroll
    for (int j = 0; j < NCHUNK; ++j) {
      const int base = (4 * j + wid) * 256;   // this wave's slice of chunk j
      int gidx = abase + base + lane * 4; gidx = gidx < Ecap ? gidx : Ecap;
      stage16(scores + gidx, &sS[base]);
      stage16(resid + gidx, &sR[base]);
    }

    // ---- chunk-pipelined AB: t = log(w)+r; online 4-tuple -----------------
    float c[NCHUNK][4];                  // t (or LARGE_NEG); static indexing
    float smax = 0.f, ssum = 0.f, vc = 0.f, tmax = LARGE_NEG;

#define DO_CHUNK(J)                                                          \
    {                                                                        \
      const int e0 = abase + J * 1024 + t4;                                  \
      const float4 s4 = *(const float4*)&sS[J * 1024 + t4];                  \
      const float4 r4 = *(const float4*)&sR[J * 1024 + t4];                  \
      unsigned int m;                                                        \
      if (byteFmt) {                                                         \
        const unsigned int u = vw[J];                                        \
        m = ((u & 0x000000FFu) ? 1u : 0u) | ((u & 0x0000FF00u) ? 2u : 0u) |  \
            ((u & 0x00FF0000u) ? 4u : 0u) | ((u & 0xFF000000u) ? 8u : 0u);   \
      } else {                                                               \
        m = (vq[J].x ? 1u : 0u) | (vq[J].y ? 2u : 0u) |                      \
            (vq[J].z ? 4u : 0u) | (vq[J].w ? 8u : 0u);                       \
      }                                                                      \
      const float ss[4] = {s4.x, s4.y, s4.z, s4.w};                          \
      const float rr[4] = {r4.x, r4.y, r4.z, r4.w};                          \
      _Pragma("unroll")                                                      \
      for (int k = 0; k < 4; ++k) {                                          \
        const int e = e0 + k;                                                \
        const bool ok = ((m >> k) & 1u) && (e >= start) && (e < end);        \
        const float w = ok ? fmaxf(ss[k], SCORE_EPS) : 0.f;                  \
        smax = fmaxf(smax, w);                                               \
        ssum += w;                                                           \
        vc += ok ? 1.f : 0.f;                                                \
        const float t = ok ? (__logf(w) + rr[k]) : LARGE_NEG;                \
        c[J][k] = t;                                                         \
        tmax = fmaxf(tmax, t);                                               \
      }                                                                      \
    }

    WAITV(8); DO_CHUNK(0);
    WAITV(6); DO_CHUNK(1);
    WAITV(4); DO_CHUNK(2);
    WAITV(2); DO_CHUNK(3);
    WAITV(0); DO_CHUNK(4);
#undef DO_CHUNK

    __syncthreads();                     // all waves drained; sS alias safe
#pragma unroll
    for (int o = 32; o >= 1; o >>= 1) {
      smax = fmaxf(smax, __shfl_xor(smax, o));
      ssum += __shfl_xor(ssum, o);
      vc += __shfl_xor(vc, o);
      tmax = fmaxf(tmax, __shfl_xor(tmax, o));
    }
    if (lane == 0) {
      redf[wid] = smax; redf[4 + wid] = ssum; redf[8 + wid] = vc;
      redf[12 + wid] = tmax;
    }
    __syncthreads();
    smax = fmaxf(fmaxf(redf[0], redf[1]), fmaxf(redf[2], redf[3]));
    ssum = (redf[4] + redf[5]) + (redf[6] + redf[7]);
    vc = (redf[8] + redf[9]) + (redf[10] + redf[11]);
    tmax = fmaxf(fmaxf(redf[12], redf[13]), fmaxf(redf[14], redf[15]));

    // ---- scalar stage-1/2 plumbing ----------------------------------------
    // exp(log(w) - mj1) == w/M with M = max(smax,1) = exp(mj1);
    // max((log w - ld1) + r) == max(log w + r) - ld1.
    const float M = fmaxf(smax, 1.f);
    const float invM = 1.f / M;
    const float ld1 = __logf(M) + __logf(ssum * invM + invM + F32EPS);
    const float m2 = tmax - ld1;             // max combined edge logit
    const float ss2 = stop_resid[g] - ld1;   // combined stop logit
    const float mj2 = fmaxf(m2, ss2);
    const float off2 = ld1 + mj2;            // exp(c - mj2) = exp(t - off2)

    // ---- phase C (regs only): denominator + argmax fused ------------------
    // argmax over t == argmax over log_sample_edge (strictly monotone chain).
    float s2 = 0.f, bv = -INFINITY;
    int bi = INT_MAX;
#pragma unroll
    for (int j = 0; j < NCHUNK; ++j)
#pragma unroll
      for (int k = 0; k < 4; ++k) {
        const float t = c[j][k];
        s2 += __expf(t - off2);              // inert -> 0
        const int e = abase + j * 1024 + t4 + k;
        if (t != LARGE_NEG && (t > bv || (t == bv && e < bi))) { bv = t; bi = e; }
      }
#pragma unroll
    for (int o = 32; o >= 1; o >>= 1) {
      s2 += __shfl_xor(s2, o);
      const float v2 = __shfl_xor(bv, o);
      const int i2 = __shfl_xor(bi, o);
      if (v2 > bv || (v2 == bv && i2 < bi)) { bv = v2; bi = i2; }
    }
    __syncthreads();                     // reduce1 reads done before reuse
    if (lane == 0) { redf2[wid] = s2; redf2[4 + wid] = bv; redi2[wid] = bi; }
    __syncthreads();
    s2 = (redf2[0] + redf2[1]) + (redf2[2] + redf2[3]);
    bv = redf2[4]; bi = redi2[0];
    for (int w = 1; w < 4; ++w) {
      const float v2 = redf2[4 + w]; const int i2 = redi2[w];
      if (v2 > bv || (v2 == bv && i2 < bi)) { bv = v2; bi = i2; }
    }
    const float ld2 = mj2 + __logf(s2 + __expf(ss2 - mj2) + F32EPS);
    const float clean_stop = ss2 - ld2;
    const float invt = 1.f / fmaxf(vc + 1.f, 1.f);
    const float off3 = ld1 + ld2;            // clean = t - off3

    // ---- phase D: stores only ---------------------------------------------
#pragma unroll
    for (int j = 0; j < NCHUNK; ++j) {
      const int e0 = abase + j * 1024 + t4;
      if (e0 < end) {
        float ov[4];
#pragma unroll
        for (int k = 0; k < 4; ++k) {
          const float t = c[j][k];
          ov[k] = (t != LARGE_NEG) ? (t - off3) : LARGE_NEG;
        }
        if (e0 >= start && e0 + 4 <= end) {
          *(float4*)(out + e0) = make_float4(ov[0], ov[1], ov[2], ov[3]);
        } else {
#pragma unroll
          for (int k = 0; k < 4; ++k) {
            const int e = e0 + k;
            if (e >= start && e < end) out[e] = ov[k];
          }
        }
      }
    }
    if (threadIdx.x == 0) {
      const bool anyvalid = (bi != INT_MAX);
      const float wclean = bv - off3;      // winner's clean_log_edge
      float bvls = LARGE_NEG;              // best log_sample_edge (ref formula)
      if (anyvalid) {
        const float p = (1.f - RANDP) * __expf(wclean) + RANDP * invt;
        bvls = __logf(fmaxf(p, PROB_EPS));
      }
      const float ssp = (1.f - RANDP) * __expf(clean_stop) + RANDP * invt;
      const float lss = __logf(fmaxf(ssp, PROB_EPS));
      const bool take_stop = (lss >= bvls);
      out[E + g]         = clean_stop;                         // output 1
      out[E + G + g]     = take_stop ? (float)end : (float)bi; // output 2
      out[E + 2 * G + g] = take_stop ? clean_stop : wclean;    // output 3
    }
    return;
  }

  // =================== fallback: 5-pass global reread (n > LDSN) ===========
  const int n = end - start;
  auto load_l = [&](int e) -> float {
    float s = scores[e];
    int v = byteFmt ? (int)vb[e] : vi[e];
    return v ? __logf(fmaxf(s, SCORE_EPS)) : LARGE_NEG;
  };

  float m1 = LARGE_NEG, vc = 0.f;
  for (int i = threadIdx.x; i < n; i += BLOCK) {
    float l = load_l(start + i);
    m1 = fmaxf(m1, l);
    if (l != LARGE_NEG) vc += 1.f;
  }
#pragma unroll
  for (int o = 32; o >= 1; o >>= 1) {
    m1 = fmaxf(m1, __shfl_xor(m1, o));
    vc += __shfl_xor(vc, o);
  }
  if (lane == 0) { redf[wid] = m1; redf[4 + wid] = vc; }
  __syncthreads();
  m1 = fmaxf(fmaxf(redf[0], redf[1]), fmaxf(redf[2], redf[3]));
  vc = (redf[4] + redf[5]) + (redf[6] + redf[7]);
  __syncthreads();

  const float mj1 = fmaxf(m1, 0.f);
  float s1 = 0.f;
  for (int i = threadIdx.x; i < n; i += BLOCK)
    s1 += __expf(load_l(start + i) - mj1);
#pragma unroll
  for (int o = 32; o >= 1; o >>= 1) s1 += __shfl_xor(s1, o);
  if (lane == 0) redf[wid] = s1;
  __syncthreads();
  s1 = (redf[0] + redf[1]) + (redf[2] + redf[3]);
  __syncthreads();
  const float ld1 = mj1 + __logf(s1 + __expf(-mj1) + F32EPS);

  float m2 = LARGE_NEG;
  for (int i = threadIdx.x; i < n; i += BLOCK) {
    float l = load_l(start + i);
    float cc = (l != LARGE_NEG) ? (l - ld1 + resid[start + i]) : LARGE_NEG;
    m2 = fmaxf(m2, cc);
  }
#pragma unroll
  for (int o = 32; o >= 1; o >>= 1) m2 = fmaxf(m2, __shfl_xor(m2, o));
  if (lane == 0) redf[wid] = m2;
  __syncthreads();
  m2 = fmaxf(fmaxf(redf[0], redf[1]), fmaxf(redf[2], redf[3]));
  __syncthreads();

  const float ss2 = stop_resid[g] - ld1;
  const float mj2 = fmaxf(m2, ss2);
  float s2 = 0.f;
  for (int i = threadIdx.x; i < n; i += BLOCK) {
    float l = load_l(start + i);
    float cc = (l != LARGE_NEG) ? (l - ld1 + resid[start + i]) : LARGE_NEG;
    s2 += __expf(cc - mj2);
  }
#pragma unroll
  for (int o = 32; o >= 1; o >>= 1) s2 += __shfl_xor(s2, o);
  if (lane == 0) redf[wid] = s2;
  __syncthreads();
  s2 = (redf[0] + redf[1]) + (redf[2] + redf[3]);
  __syncthreads();
  const float ld2 = mj2 + __logf(s2 + __expf(ss2 - mj2) + F32EPS);
  const float clean_stop = ss2 - ld2;
  const float invt = 1.f / fmaxf(vc + 1.f, 1.f);

  float bv = -INFINITY; int bi = INT_MAX; float bc = 0.f;
  for (int i = threadIdx.x; i < n; i += BLOCK) {
    const int e = start + i;
    float l = load_l(e);
    float cc = (l != LARGE_NEG) ? (l - ld1 + resid[e]) : LARGE_NEG;
    const bool v = (cc != LARGE_NEG);
    const float clean = cc - ld2;
    out[e] = v ? clean : LARGE_NEG;
    float ls;
    if (v) {
      const float p = (1.f - RANDP) * __expf(clean) + RANDP * invt;
      ls = __logf(fmaxf(p, PROB_EPS));
    } else ls = LARGE_NEG;
    if (ls > bv || (ls == bv && e < bi)) { bv = ls; bi = e; bc = clean; }
  }
#pragma unroll
  for (int o = 32; o >= 1; o >>= 1) {
    const float v2 = __shfl_xor(bv, o);
    const int i2 = __shfl_xor(bi, o);
    const float c2 = __shfl_xor(bc, o);
    if (v2 > bv || (v2 == bv && i2 < bi)) { bv = v2; bi = i2; bc = c2; }
  }
  if (lane == 0) { redf[wid] = bv; redf[4 + wid] = bc; redi[wid] = bi; }
  __syncthreads();
  if (threadIdx.x == 0) {
    bv = redf[0]; bi = redi[0]; bc = redf[4];
    for (int w = 1; w < 4; ++w) {
      if (redf[w] > bv || (redf[w] == bv && redi[w] < bi)) {
        bv = redf[w]; bi = redi[w]; bc = redf[4 + w];
      }
    }
    const float ssp = (1.f - RANDP) * __expf(clean_stop) + RANDP * invt;
    const float lss = __logf(fmaxf(ssp, PROB_EPS));
    const bool take_stop = (lss >= bv);
    out[E + g]         = clean_stop;
    out[E + G + g]     = take_stop ? (float)end : (float)bi;
    out[E + 2 * G + g] = take_stop ? clean_stop : bc;
  }
}

extern "C" void kernel_launch(void* const* d_in, const int* in_sizes, int n_in,
                              void* d_out, int out_size, void* d_ws, size_t ws_size,
                              hipStream_t stream) {
  const float* scores     = (const float*)d_in[0];
  const float* resid      = (const float*)d_in[1];
  const float* stop_resid = (const float*)d_in[2];
  const void*  validp     = d_in[3];
  const int*   batch      = (const int*)d_in[4];
  const int E = in_sizes[0];
  const int G = in_sizes[2];

  int* flag = (int*)d_ws;            // ws[0]: valid_edges format flag
  int* ptr  = (int*)d_ws + 64;       // ws[64..64+G+1): segment pointers
  float* out = (float*)d_out;

  int sample_bytes = (E < 8192) ? (E & ~3) : 8192;
  int nbPtr = (G + 1 + BLOCK - 1) / BLOCK;
  gfn_setup<<<nbPtr + 1, BLOCK, 0, stream>>>(batch, E, G, ptr,
                                             (const unsigned int*)validp,
                                             sample_bytes / 4, sample_bytes,
                                             flag, nbPtr);
  gfn_main<<<G, BLOCK, 0, stream>>>(scores, resid, stop_resid, validp, ptr,
                                    flag, out, E, G);
}

// Round 9
// 37.960 us; speedup vs baseline: 1.2278x; 1.1042x over previous
//
#include <hip/hip_runtime.h>
#include <math.h>
#include <climits>

#define BLOCK 256
#define NCHUNK 5
#define REGCAP (NCHUNK * 1024)          // 5120 aligned elements per block
#define LARGE_NEG (-1.0e9f)
#define SCORE_EPS 1e-6f
#define RANDP 0.1f
#define PROB_EPS 1e-12f
#define F32EPS 1.1920928955078125e-7f   // torch.finfo(float32).eps

// ---------- kernel 1: fused setup ------------------------------------------
// Blocks [0, nbPtr): ptr via windowed binary search (edge_batch sorted;
//   window g*E/G +/- 16384, verified, full-range fallback).
// Block nbPtr: valid_edges storage-format detect on an 8 KB sample.
__global__ void gfn_setup(const int* __restrict__ batch, int E, int G,
                          int* __restrict__ ptr,
                          const unsigned int* __restrict__ vwords, int nwords,
                          int nbytes, int* __restrict__ flag, int nbPtr) {
  if ((int)blockIdx.x < nbPtr) {
    int g = blockIdx.x * BLOCK + threadIdx.x;
    if (g > G) return;
    long long ghat = (long long)g * (long long)E / (long long)(G > 0 ? G : 1);
    long long wlo = ghat - 16384, whi = ghat + 16384;
    int lo = wlo > 0 ? (int)wlo : 0;
    int hi = whi < (long long)E ? (int)whi : E;
    while (lo < hi) {
      int mid = (lo + hi) >> 1;
      if (batch[mid] < g) lo = mid + 1; else hi = mid;
    }
    int r = lo;
    bool ok = (r == 0 || batch[r - 1] < g) && (r == E || batch[r] >= g);
    if (!ok) {                          // window missed: full-range redo
      lo = 0; hi = E;
      while (lo < hi) {
        int mid = (lo + hi) >> 1;
        if (batch[mid] < g) lo = mid + 1; else hi = mid;
      }
      r = lo;
    }
    ptr[g] = r;   // first edge with batch >= g; segment g = [ptr[g], ptr[g+1])
  } else {
    int c = 0;
    for (int i = threadIdx.x; i < nwords; i += BLOCK) {
      unsigned int w = vwords[i];
      c += ((w & 0x000000FFu) != 0) + ((w & 0x0000FF00u) != 0) +
           ((w & 0x00FF0000u) != 0) + ((w & 0xFF000000u) != 0);
    }
#pragma unroll
    for (int o = 32; o >= 1; o >>= 1) c += __shfl_xor(c, o);
    __shared__ int part[4];
    if ((threadIdx.x & 63) == 0) part[threadIdx.x >> 6] = c;
    __syncthreads();
    if (threadIdx.x == 0) {
      int t = part[0] + part[1] + part[2] + part[3];
      flag[0] = (2 * t > nbytes) ? 1 : 0;
    }
  }
}

// ---------- kernel 2: one workgroup per graph, online single-barrier -------
// Load pass: predicated direct float4 loads; per element t = log(w)+r with
//   ONLINE softmax accumulation (om, os): os += exp(t-om), rescale on new max
//   (amortized ~1 exp/edge). Also smax/ssum/vc and argmax-by-t inline.
//   -> phase C and ALL extra reduce rounds are gone.
// One fused reduce: shuffle cascade over 7 quantities, lane0 -> LDS, ONE
//   __syncthreads, every thread merges 4 wave-partials and computes the
//   per-graph scalars locally.
// Store pass: clean = t - off3 from registers.
__global__ __launch_bounds__(BLOCK) void
gfn_main(const float* __restrict__ scores,
         const float* __restrict__ resid,
         const float* __restrict__ stop_resid,
         const void* __restrict__ validp,
         const int* __restrict__ ptr,
         const int* __restrict__ flag,
         float* __restrict__ out, int E, int G) {
  __shared__ float redf[24];
  __shared__ int redi[4];

  const int g = blockIdx.x;
  const int start = ptr[g];
  const int end = ptr[g + 1];
  const bool byteFmt = (flag[0] != 0);
  const unsigned char* vb = (const unsigned char*)validp;
  const int* vi = (const int*)validp;
  const int abase = start & ~3;          // 16B-aligned segment base
  const int wid = (int)(threadIdx.x >> 6);
  const int lane = (int)(threadIdx.x & 63);

  if ((E & 3) == 0 && (end - abase) <= REGCAP) {
    // =================== fast path: t in registers, online reduce ==========
    const int t4 = (int)threadIdx.x * 4;
    float c[NCHUNK][4];                  // t (or LARGE_NEG), static indexing
    float smax = 0.f, ssum = 0.f;
    int vcnt = 0;
    float om = LARGE_NEG, os = 0.f;      // online (max, expsum) over t
    float bv = -INFINITY;                // argmax over t (monotone equiv to
    int bi = INT_MAX;                    //   reference log_sample argmax)

#pragma unroll
    for (int j = 0; j < NCHUNK; ++j) {
      const int e0 = abase + j * 1024 + t4;
      if (e0 < end) {   // e0%4==0 & E%4==0 -> e0+3 <= E-1 (safe f4 load)
        const float4 s4 = *(const float4*)(scores + e0);
        const float4 r4 = *(const float4*)(resid + e0);
        unsigned int m;
        if (byteFmt) {
          const unsigned int u = *(const unsigned int*)(vb + e0);
          m = ((u & 0x000000FFu) ? 1u : 0u) | ((u & 0x0000FF00u) ? 2u : 0u) |
              ((u & 0x00FF0000u) ? 4u : 0u) | ((u & 0xFF000000u) ? 8u : 0u);
        } else {
          const int4 u = *(const int4*)(vi + e0);
          m = (u.x ? 1u : 0u) | (u.y ? 2u : 0u) | (u.z ? 4u : 0u) | (u.w ? 8u : 0u);
        }
        const float ss[4] = {s4.x, s4.y, s4.z, s4.w};
        const float rr[4] = {r4.x, r4.y, r4.z, r4.w};
#pragma unroll
        for (int k = 0; k < 4; ++k) {
          const int e = e0 + k;
          const bool ok = ((m >> k) & 1u) && (e >= start) && (e < end);
          float t = LARGE_NEG;
          if (ok) {
            const float w = fmaxf(ss[k], SCORE_EPS);
            smax = fmaxf(smax, w);
            ssum += w;
            ++vcnt;
            t = __logf(w) + rr[k];
            if (t > om) {                // max grew: rescale (amortized rare)
              os = os * __expf(om - t) + 1.f;   // exp(-1e9-t)==0 on first
              om = t;
            } else {
              os += __expf(t - om);
            }
            if (t > bv || (t == bv && e < bi)) { bv = t; bi = e; }
          }
          c[j][k] = t;
        }
      } else {
#pragma unroll
        for (int k = 0; k < 4; ++k) c[j][k] = LARGE_NEG;
      }
    }

    // ---- single fused reduce: wave shuffle cascade over everything --------
#pragma unroll
    for (int o = 32; o >= 1; o >>= 1) {
      smax = fmaxf(smax, __shfl_xor(smax, o));
      ssum += __shfl_xor(ssum, o);
      vcnt += __shfl_xor(vcnt, o);
      const float m2v = __shfl_xor(om, o);
      const float s2v = __shfl_xor(os, o);
      const float nm = fmaxf(om, m2v);
      os = os * __expf(om - nm) + s2v * __expf(m2v - nm);
      om = nm;
      const float v2 = __shfl_xor(bv, o);
      const int i2 = __shfl_xor(bi, o);
      if (v2 > bv || (v2 == bv && i2 < bi)) { bv = v2; bi = i2; }
    }
    if (lane == 0) {
      redf[wid] = smax; redf[4 + wid] = ssum; redf[8 + wid] = (float)vcnt;
      redf[12 + wid] = om; redf[16 + wid] = os; redf[20 + wid] = bv;
      redi[wid] = bi;
    }
    __syncthreads();                     // the ONLY barrier in the fast path
    smax = fmaxf(fmaxf(redf[0], redf[1]), fmaxf(redf[2], redf[3]));
    ssum = (redf[4] + redf[5]) + (redf[6] + redf[7]);
    const float vc = (redf[8] + redf[9]) + (redf[10] + redf[11]);
    om = redf[12]; os = redf[16];
#pragma unroll
    for (int w = 1; w < 4; ++w) {        // online-merge 4 wave pairs
      const float mb = redf[12 + w], sb = redf[16 + w];
      const float nm = fmaxf(om, mb);
      os = os * __expf(om - nm) + sb * __expf(mb - nm);
      om = nm;
    }
    bv = redf[20]; bi = redi[0];
#pragma unroll
    for (int w = 1; w < 4; ++w) {
      const float v2 = redf[20 + w]; const int i2 = redi[w];
      if (v2 > bv || (v2 == bv && i2 < bi)) { bv = v2; bi = i2; }
    }

    // ---- per-graph scalars (computed by every thread; all scalar math) ----
    // exp(log w - mj1) == w/M with M = max(smax,1) = exp(mj1);
    // max((log w - ld1) + r) == tmax - ld1;  Sum exp(c-mj2) == os*exp(m2-mj2).
    const float M = fmaxf(smax, 1.f);
    const float invM = 1.f / M;
    const float ld1 = __logf(M) + __logf(ssum * invM + invM + F32EPS);
    const float m2 = om - ld1;               // max combined edge logit
    const float ss2 = stop_resid[g] - ld1;   // combined stop logit
    const float mj2 = fmaxf(m2, ss2);
    const float s2 = os * __expf(m2 - mj2);  // edge exp-sum at mj2 scale
    const float ld2 = mj2 + __logf(s2 + __expf(ss2 - mj2) + F32EPS);
    const float clean_stop = ss2 - ld2;
    const float invt = 1.f / fmaxf(vc + 1.f, 1.f);
    const float off3 = ld1 + ld2;            // clean = t - off3

    // ---- store pass: clean_log_edge from registers ------------------------
#pragma unroll
    for (int j = 0; j < NCHUNK; ++j) {
      const int e0 = abase + j * 1024 + t4;
      if (e0 < end) {
        float ov[4];
#pragma unroll
        for (int k = 0; k < 4; ++k) {
          const float t = c[j][k];
          ov[k] = (t != LARGE_NEG) ? (t - off3) : LARGE_NEG;
        }
        if (e0 >= start && e0 + 4 <= end) {
          *(float4*)(out + e0) = make_float4(ov[0], ov[1], ov[2], ov[3]);
        } else {
#pragma unroll
          for (int k = 0; k < 4; ++k) {
            const int e = e0 + k;
            if (e >= start && e < end) out[e] = ov[k];
          }
        }
      }
    }
    if (threadIdx.x == 0) {
      const bool anyvalid = (bi != INT_MAX);
      const float wclean = bv - off3;      // winner's clean_log_edge
      float bvls = LARGE_NEG;              // best log_sample_edge (ref formula)
      if (anyvalid) {
        const float p = (1.f - RANDP) * __expf(wclean) + RANDP * invt;
        bvls = __logf(fmaxf(p, PROB_EPS));
      }
      const float ssp = (1.f - RANDP) * __expf(clean_stop) + RANDP * invt;
      const float lss = __logf(fmaxf(ssp, PROB_EPS));
      const bool take_stop = (lss >= bvls);
      out[E + g]         = clean_stop;                         // output 1
      out[E + G + g]     = take_stop ? (float)end : (float)bi; // output 2
      out[E + 2 * G + g] = take_stop ? clean_stop : wclean;    // output 3
    }
    return;
  }

  // =================== fallback: 5-pass global reread (n > REGCAP) =========
  const int n = end - start;
  auto load_l = [&](int e) -> float {
    float s = scores[e];
    int v = byteFmt ? (int)vb[e] : vi[e];
    return v ? __logf(fmaxf(s, SCORE_EPS)) : LARGE_NEG;
  };

  float m1 = LARGE_NEG, vc = 0.f;
  for (int i = threadIdx.x; i < n; i += BLOCK) {
    float l = load_l(start + i);
    m1 = fmaxf(m1, l);
    if (l != LARGE_NEG) vc += 1.f;
  }
#pragma unroll
  for (int o = 32; o >= 1; o >>= 1) {
    m1 = fmaxf(m1, __shfl_xor(m1, o));
    vc += __shfl_xor(vc, o);
  }
  if (lane == 0) { redf[wid] = m1; redf[4 + wid] = vc; }
  __syncthreads();
  m1 = fmaxf(fmaxf(redf[0], redf[1]), fmaxf(redf[2], redf[3]));
  vc = (redf[4] + redf[5]) + (redf[6] + redf[7]);
  __syncthreads();

  const float mj1 = fmaxf(m1, 0.f);
  float s1 = 0.f;
  for (int i = threadIdx.x; i < n; i += BLOCK)
    s1 += __expf(load_l(start + i) - mj1);
#pragma unroll
  for (int o = 32; o >= 1; o >>= 1) s1 += __shfl_xor(s1, o);
  if (lane == 0) redf[wid] = s1;
  __syncthreads();
  s1 = (redf[0] + redf[1]) + (redf[2] + redf[3]);
  __syncthreads();
  const float ld1 = mj1 + __logf(s1 + __expf(-mj1) + F32EPS);

  float m2 = LARGE_NEG;
  for (int i = threadIdx.x; i < n; i += BLOCK) {
    float l = load_l(start + i);
    float cc = (l != LARGE_NEG) ? (l - ld1 + resid[start + i]) : LARGE_NEG;
    m2 = fmaxf(m2, cc);
  }
#pragma unroll
  for (int o = 32; o >= 1; o >>= 1) m2 = fmaxf(m2, __shfl_xor(m2, o));
  if (lane == 0) redf[wid] = m2;
  __syncthreads();
  m2 = fmaxf(fmaxf(redf[0], redf[1]), fmaxf(redf[2], redf[3]));
  __syncthreads();

  const float ss2 = stop_resid[g] - ld1;
  const float mj2 = fmaxf(m2, ss2);
  float s2 = 0.f;
  for (int i = threadIdx.x; i < n; i += BLOCK) {
    float l = load_l(start + i);
    float cc = (l != LARGE_NEG) ? (l - ld1 + resid[start + i]) : LARGE_NEG;
    s2 += __expf(cc - mj2);
  }
#pragma unroll
  for (int o = 32; o >= 1; o >>= 1) s2 += __shfl_xor(s2, o);
  if (lane == 0) redf[wid] = s2;
  __syncthreads();
  s2 = (redf[0] + redf[1]) + (redf[2] + redf[3]);
  __syncthreads();
  const float ld2 = mj2 + __logf(s2 + __expf(ss2 - mj2) + F32EPS);
  const float clean_stop = ss2 - ld2;
  const float invt = 1.f / fmaxf(vc + 1.f, 1.f);

  float bv = -INFINITY; int bi = INT_MAX; float bc = 0.f;
  for (int i = threadIdx.x; i < n; i += BLOCK) {
    const int e = start + i;
    float l = load_l(e);
    float cc = (l != LARGE_NEG) ? (l - ld1 + resid[e]) : LARGE_NEG;
    const bool v = (cc != LARGE_NEG);
    const float clean = cc - ld2;
    out[e] = v ? clean : LARGE_NEG;
    float ls;
    if (v) {
      const float p = (1.f - RANDP) * __expf(clean) + RANDP * invt;
      ls = __logf(fmaxf(p, PROB_EPS));
    } else ls = LARGE_NEG;
    if (ls > bv || (ls == bv && e < bi)) { bv = ls; bi = e; bc = clean; }
  }
#pragma unroll
  for (int o = 32; o >= 1; o >>= 1) {
    const float v2 = __shfl_xor(bv, o);
    const int i2 = __shfl_xor(bi, o);
    const float c2 = __shfl_xor(bc, o);
    if (v2 > bv || (v2 == bv && i2 < bi)) { bv = v2; bi = i2; bc = c2; }
  }
  if (lane == 0) { redf[wid] = bv; redf[4 + wid] = bc; redi[wid] = bi; }
  __syncthreads();
  if (threadIdx.x == 0) {
    bv = redf[0]; bi = redi[0]; bc = redf[4];
    for (int w = 1; w < 4; ++w) {
      if (redf[w] > bv || (redf[w] == bv && redi[w] < bi)) {
        bv = redf[w]; bi = redi[w]; bc = redf[4 + w];
      }
    }
    const float ssp = (1.f - RANDP) * __expf(clean_stop) + RANDP * invt;
    const float lss = __logf(fmaxf(ssp, PROB_EPS));
    const bool take_stop = (lss >= bv);
    out[E + g]         = clean_stop;
    out[E + G + g]     = take_stop ? (float)end : (float)bi;
    out[E + 2 * G + g] = take_stop ? clean_stop : bc;
  }
}

extern "C" void kernel_launch(void* const* d_in, const int* in_sizes, int n_in,
                              void* d_out, int out_size, void* d_ws, size_t ws_size,
                              hipStream_t stream) {
  const float* scores     = (const float*)d_in[0];
  const float* resid      = (const float*)d_in[1];
  const float* stop_resid = (const float*)d_in[2];
  const void*  validp     = d_in[3];
  const int*   batch      = (const int*)d_in[4];
  const int E = in_sizes[0];
  const int G = in_sizes[2];

  int* flag = (int*)d_ws;            // ws[0]: valid_edges format flag
  int* ptr  = (int*)d_ws + 64;       // ws[64..64+G+1): segment pointers
  float* out = (float*)d_out;

  int sample_bytes = (E < 8192) ? (E & ~3) : 8192;
  int nbPtr = (G + 1 + BLOCK - 1) / BLOCK;
  gfn_setup<<<nbPtr + 1, BLOCK, 0, stream>>>(batch, E, G, ptr,
                                             (const unsigned int*)validp,
                                             sample_bytes / 4, sample_bytes,
                                             flag, nbPtr);
  gfn_main<<<G, BLOCK, 0, stream>>>(scores, resid, stop_resid, validp, ptr,
                                    flag, out, E, G);
}

// Round 10
// 33.238 us; speedup vs baseline: 1.4022x; 1.1421x over previous
//
#include <hip/hip_runtime.h>
#include <math.h>
#include <climits>

#define BLOCK 256
#define NCHUNK 5
#define REGCAP (NCHUNK * 1024)          // 5120 aligned elements per block
#define LARGE_NEG (-1.0e9f)
#define SCORE_EPS 1e-6f
#define RANDP 0.1f
#define PROB_EPS 1e-12f
#define F32EPS 1.1920928955078125e-7f   // torch.finfo(float32).eps

// scalar windowed lower_bound: first idx with batch[idx] >= target.
// Window ghat +/- 16384 (>11 sigma for multinomial edge counts), verified,
// full-range fallback so correctness never depends on the distribution.
__device__ __forceinline__ int scalar_lb(const int* __restrict__ batch,
                                         int E, int G, int target) {
  const long long ghat =
      (long long)target * (long long)E / (long long)(G > 0 ? G : 1);
  long long wlo = ghat - 16384, whi = ghat + 16384;
  int lo = wlo > 0 ? (int)wlo : 0;
  int hi = whi < (long long)E ? (int)whi : E;
  while (lo < hi) {
    const int mid = (lo + hi) >> 1;
    if (batch[mid] < target) lo = mid + 1; else hi = mid;
  }
  bool ok = (lo == 0 || batch[lo - 1] < target) &&
            (lo == E || batch[lo] >= target);
  if (!ok) {                            // window missed: full-range redo
    lo = 0; hi = E;
    while (lo < hi) {
      const int mid = (lo + hi) >> 1;
      if (batch[mid] < target) lo = mid + 1; else hi = mid;
    }
  }
  return lo;
}

// ---------- single kernel: one workgroup per graph -------------------------
// Prologue (concurrent, one barrier): thread 0 -> start = lb(g) on SIMD0;
//   thread 64 -> end = lb(g+1) on SIMD1; wave 2 -> valid_edges format detect
//   on a shared 1KB sample (byte-bool ~90% nonzero bytes | int32 ~22.5% |
//   f32 ~45%; threshold 50%). All 2048 block-prologues run concurrently, so
//   the old setup-kernel's serial launch + search chain leaves the critical
//   path, and jitter desynchronizes the blocks' load/store phases.
// Body (r9): predicated float4 loads; t = log(w)+r with BRANCHLESS online
//   softmax (om, os); smax/ssum/vcnt/argmax inline; ONE fused reduce round;
//   scalar plumbing; store pass from registers.
__global__ __launch_bounds__(BLOCK) void
gfn_main(const float* __restrict__ scores,
         const float* __restrict__ resid,
         const float* __restrict__ stop_resid,
         const void* __restrict__ validp,
         const int* __restrict__ batch,
         float* __restrict__ out, int E, int G) {
  __shared__ float redf[24];
  __shared__ int redi[4];
  __shared__ int sb[2];
  __shared__ int sflag;

  const int g = blockIdx.x;
  const unsigned char* vb = (const unsigned char*)validp;
  const int* vi = (const int*)validp;
  const int wid = (int)(threadIdx.x >> 6);
  const int lane = (int)(threadIdx.x & 63);

  // ---- fused prologue ----
  if (threadIdx.x == 0) {
    sb[0] = scalar_lb(batch, E, G, g);
  } else if (threadIdx.x == 64) {
    sb[1] = scalar_lb(batch, E, G, g + 1);
  } else if (wid == 2) {
    const unsigned int* vwords = (const unsigned int*)validp;
    const int sampleBytes = (E < 1024) ? (E & ~3) : 1024;
    const int nwords = sampleBytes >> 2;
    int cnt = 0;
    for (int w = lane; w < nwords; w += 64) {
      const unsigned int x = vwords[w];
      cnt += ((x & 0x000000FFu) != 0) + ((x & 0x0000FF00u) != 0) +
             ((x & 0x00FF0000u) != 0) + ((x & 0xFF000000u) != 0);
    }
#pragma unroll
    for (int o = 32; o >= 1; o >>= 1) cnt += __shfl_xor(cnt, o);
    if (lane == 0) sflag = (2 * cnt > sampleBytes) ? 1 : 0;
  }
  __syncthreads();
  const int start = sb[0];
  const int end = sb[1];
  const bool byteFmt = (sflag != 0);
  const int abase = start & ~3;          // 16B-aligned segment base

  if ((E & 3) == 0 && (end - abase) <= REGCAP) {
    // =================== fast path: t in registers, online reduce ==========
    const int t4 = (int)threadIdx.x * 4;
    float c[NCHUNK][4];                  // t (or LARGE_NEG), static indexing
    float smax = 0.f, ssum = 0.f;
    int vcnt = 0;
    float om = LARGE_NEG, os = 0.f;      // online (max, expsum) over t
    float bv = -INFINITY;                // argmax over t (monotone equiv to
    int bi = INT_MAX;                    //   reference log_sample argmax)

#pragma unroll
    for (int j = 0; j < NCHUNK; ++j) {
      const int e0 = abase + j * 1024 + t4;
      if (e0 < end) {   // e0%4==0 & E%4==0 -> e0+3 <= E-1 (safe f4 load)
        const float4 s4 = *(const float4*)(scores + e0);
        const float4 r4 = *(const float4*)(resid + e0);
        unsigned int m;
        if (byteFmt) {
          const unsigned int u = *(const unsigned int*)(vb + e0);
          m = ((u & 0x000000FFu) ? 1u : 0u) | ((u & 0x0000FF00u) ? 2u : 0u) |
              ((u & 0x00FF0000u) ? 4u : 0u) | ((u & 0xFF000000u) ? 8u : 0u);
        } else {
          const int4 u = *(const int4*)(vi + e0);
          m = (u.x ? 1u : 0u) | (u.y ? 2u : 0u) | (u.z ? 4u : 0u) | (u.w ? 8u : 0u);
        }
        const float ss[4] = {s4.x, s4.y, s4.z, s4.w};
        const float rr[4] = {r4.x, r4.y, r4.z, r4.w};
#pragma unroll
        for (int k = 0; k < 4; ++k) {
          const int e = e0 + k;
          const bool ok = ((m >> k) & 1u) && (e >= start) && (e < end);
          float t = LARGE_NEG;
          if (ok) {
            const float w = fmaxf(ss[k], SCORE_EPS);
            smax = fmaxf(smax, w);
            ssum += w;
            ++vcnt;
            t = __logf(w) + rr[k];
            // branchless online update (no divergent dual-exp paths)
            const float nm = fmaxf(om, t);
            os = os * __expf(om - nm) + __expf(t - nm);  // first iter: 0*0+1
            om = nm;
            if (t > bv || (t == bv && e < bi)) { bv = t; bi = e; }
          }
          c[j][k] = t;
        }
      } else {
#pragma unroll
        for (int k = 0; k < 4; ++k) c[j][k] = LARGE_NEG;
      }
    }

    // ---- single fused reduce: wave shuffle cascade over everything --------
#pragma unroll
    for (int o = 32; o >= 1; o >>= 1) {
      smax = fmaxf(smax, __shfl_xor(smax, o));
      ssum += __shfl_xor(ssum, o);
      vcnt += __shfl_xor(vcnt, o);
      const float m2v = __shfl_xor(om, o);
      const float s2v = __shfl_xor(os, o);
      const float nm = fmaxf(om, m2v);
      os = os * __expf(om - nm) + s2v * __expf(m2v - nm);
      om = nm;
      const float v2 = __shfl_xor(bv, o);
      const int i2 = __shfl_xor(bi, o);
      if (v2 > bv || (v2 == bv && i2 < bi)) { bv = v2; bi = i2; }
    }
    if (lane == 0) {
      redf[wid] = smax; redf[4 + wid] = ssum; redf[8 + wid] = (float)vcnt;
      redf[12 + wid] = om; redf[16 + wid] = os; redf[20 + wid] = bv;
      redi[wid] = bi;
    }
    __syncthreads();
    smax = fmaxf(fmaxf(redf[0], redf[1]), fmaxf(redf[2], redf[3]));
    ssum = (redf[4] + redf[5]) + (redf[6] + redf[7]);
    const float vc = (redf[8] + redf[9]) + (redf[10] + redf[11]);
    om = redf[12]; os = redf[16];
#pragma unroll
    for (int w = 1; w < 4; ++w) {        // online-merge 4 wave pairs
      const float mb = redf[12 + w], sb2 = redf[16 + w];
      const float nm = fmaxf(om, mb);
      os = os * __expf(om - nm) + sb2 * __expf(mb - nm);
      om = nm;
    }
    bv = redf[20]; bi = redi[0];
#pragma unroll
    for (int w = 1; w < 4; ++w) {
      const float v2 = redf[20 + w]; const int i2 = redi[w];
      if (v2 > bv || (v2 == bv && i2 < bi)) { bv = v2; bi = i2; }
    }

    // ---- per-graph scalars (computed by every thread; all scalar math) ----
    // exp(log w - mj1) == w/M with M = max(smax,1) = exp(mj1);
    // max((log w - ld1) + r) == tmax - ld1;  Sum exp(c-mj2) == os*exp(m2-mj2).
    const float M = fmaxf(smax, 1.f);
    const float invM = 1.f / M;
    const float ld1 = __logf(M) + __logf(ssum * invM + invM + F32EPS);
    const float m2 = om - ld1;               // max combined edge logit
    const float ss2 = stop_resid[g] - ld1;   // combined stop logit
    const float mj2 = fmaxf(m2, ss2);
    const float s2 = os * __expf(m2 - mj2);  // edge exp-sum at mj2 scale
    const float ld2 = mj2 + __logf(s2 + __expf(ss2 - mj2) + F32EPS);
    const float clean_stop = ss2 - ld2;
    const float invt = 1.f / fmaxf(vc + 1.f, 1.f);
    const float off3 = ld1 + ld2;            // clean = t - off3

    // ---- store pass: clean_log_edge from registers ------------------------
#pragma unroll
    for (int j = 0; j < NCHUNK; ++j) {
      const int e0 = abase + j * 1024 + t4;
      if (e0 < end) {
        float ov[4];
#pragma unroll
        for (int k = 0; k < 4; ++k) {
          const float t = c[j][k];
          ov[k] = (t != LARGE_NEG) ? (t - off3) : LARGE_NEG;
        }
        if (e0 >= start && e0 + 4 <= end) {
          *(float4*)(out + e0) = make_float4(ov[0], ov[1], ov[2], ov[3]);
        } else {
#pragma unroll
          for (int k = 0; k < 4; ++k) {
            const int e = e0 + k;
            if (e >= start && e < end) out[e] = ov[k];
          }
        }
      }
    }
    if (threadIdx.x == 0) {
      const bool anyvalid = (bi != INT_MAX);
      const float wclean = bv - off3;      // winner's clean_log_edge
      float bvls = LARGE_NEG;              // best log_sample_edge (ref formula)
      if (anyvalid) {
        const float p = (1.f - RANDP) * __expf(wclean) + RANDP * invt;
        bvls = __logf(fmaxf(p, PROB_EPS));
      }
      const float ssp = (1.f - RANDP) * __expf(clean_stop) + RANDP * invt;
      const float lss = __logf(fmaxf(ssp, PROB_EPS));
      const bool take_stop = (lss >= bvls);
      out[E + g]         = clean_stop;                         // output 1
      out[E + G + g]     = take_stop ? (float)end : (float)bi; // output 2
      out[E + 2 * G + g] = take_stop ? clean_stop : wclean;    // output 3
    }
    return;
  }

  // =================== fallback: 5-pass global reread (n > REGCAP) =========
  const int n = end - start;
  auto load_l = [&](int e) -> float {
    float s = scores[e];
    int v = byteFmt ? (int)vb[e] : vi[e];
    return v ? __logf(fmaxf(s, SCORE_EPS)) : LARGE_NEG;
  };

  float m1 = LARGE_NEG, vc = 0.f;
  for (int i = threadIdx.x; i < n; i += BLOCK) {
    float l = load_l(start + i);
    m1 = fmaxf(m1, l);
    if (l != LARGE_NEG) vc += 1.f;
  }
#pragma unroll
  for (int o = 32; o >= 1; o >>= 1) {
    m1 = fmaxf(m1, __shfl_xor(m1, o));
    vc += __shfl_xor(vc, o);
  }
  if (lane == 0) { redf[wid] = m1; redf[4 + wid] = vc; }
  __syncthreads();
  m1 = fmaxf(fmaxf(redf[0], redf[1]), fmaxf(redf[2], redf[3]));
  vc = (redf[4] + redf[5]) + (redf[6] + redf[7]);
  __syncthreads();

  const float mj1 = fmaxf(m1, 0.f);
  float s1 = 0.f;
  for (int i = threadIdx.x; i < n; i += BLOCK)
    s1 += __expf(load_l(start + i) - mj1);
#pragma unroll
  for (int o = 32; o >= 1; o >>= 1) s1 += __shfl_xor(s1, o);
  if (lane == 0) redf[wid] = s1;
  __syncthreads();
  s1 = (redf[0] + redf[1]) + (redf[2] + redf[3]);
  __syncthreads();
  const float ld1 = mj1 + __logf(s1 + __expf(-mj1) + F32EPS);

  float m2 = LARGE_NEG;
  for (int i = threadIdx.x; i < n; i += BLOCK) {
    float l = load_l(start + i);
    float cc = (l != LARGE_NEG) ? (l - ld1 + resid[start + i]) : LARGE_NEG;
    m2 = fmaxf(m2, cc);
  }
#pragma unroll
  for (int o = 32; o >= 1; o >>= 1) m2 = fmaxf(m2, __shfl_xor(m2, o));
  if (lane == 0) redf[wid] = m2;
  __syncthreads();
  m2 = fmaxf(fmaxf(redf[0], redf[1]), fmaxf(redf[2], redf[3]));
  __syncthreads();

  const float ss2 = stop_resid[g] - ld1;
  const float mj2 = fmaxf(m2, ss2);
  float s2 = 0.f;
  for (int i = threadIdx.x; i < n; i += BLOCK) {
    float l = load_l(start + i);
    float cc = (l != LARGE_NEG) ? (l - ld1 + resid[start + i]) : LARGE_NEG;
    s2 += __expf(cc - mj2);
  }
#pragma unroll
  for (int o = 32; o >= 1; o >>= 1) s2 += __shfl_xor(s2, o);
  if (lane == 0) redf[wid] = s2;
  __syncthreads();
  s2 = (redf[0] + redf[1]) + (redf[2] + redf[3]);
  __syncthreads();
  const float ld2 = mj2 + __logf(s2 + __expf(ss2 - mj2) + F32EPS);
  const float clean_stop = ss2 - ld2;
  const float invt = 1.f / fmaxf(vc + 1.f, 1.f);

  float bv = -INFINITY; int bi = INT_MAX; float bc = 0.f;
  for (int i = threadIdx.x; i < n; i += BLOCK) {
    const int e = start + i;
    float l = load_l(e);
    float cc = (l != LARGE_NEG) ? (l - ld1 + resid[e]) : LARGE_NEG;
    const bool v = (cc != LARGE_NEG);
    const float clean = cc - ld2;
    out[e] = v ? clean : LARGE_NEG;
    float ls;
    if (v) {
      const float p = (1.f - RANDP) * __expf(clean) + RANDP * invt;
      ls = __logf(fmaxf(p, PROB_EPS));
    } else ls = LARGE_NEG;
    if (ls > bv || (ls == bv && e < bi)) { bv = ls; bi = e; bc = clean; }
  }
#pragma unroll
  for (int o = 32; o >= 1; o >>= 1) {
    const float v2 = __shfl_xor(bv, o);
    const int i2 = __shfl_xor(bi, o);
    const float c2 = __shfl_xor(bc, o);
    if (v2 > bv || (v2 == bv && i2 < bi)) { bv = v2; bi = i2; bc = c2; }
  }
  if (lane == 0) { redf[wid] = bv; redf[4 + wid] = bc; redi[wid] = bi; }
  __syncthreads();
  if (threadIdx.x == 0) {
    bv = redf[0]; bi = redi[0]; bc = redf[4];
    for (int w = 1; w < 4; ++w) {
      if (redf[w] > bv || (redf[w] == bv && redi[w] < bi)) {
        bv = redf[w]; bi = redi[w]; bc = redf[4 + w];
      }
    }
    const float ssp = (1.f - RANDP) * __expf(clean_stop) + RANDP * invt;
    const float lss = __logf(fmaxf(ssp, PROB_EPS));
    const bool take_stop = (lss >= bv);
    out[E + g]         = clean_stop;
    out[E + G + g]     = take_stop ? (float)end : (float)bi;
    out[E + 2 * G + g] = take_stop ? clean_stop : bc;
  }
}

extern "C" void kernel_launch(void* const* d_in, const int* in_sizes, int n_in,
                              void* d_out, int out_size, void* d_ws, size_t ws_size,
                              hipStream_t stream) {
  const float* scores     = (const float*)d_in[0];
  const float* resid      = (const float*)d_in[1];
  const float* stop_resid = (const float*)d_in[2];
  const void*  validp     = d_in[3];
  const int*   batch      = (const int*)d_in[4];
  const int E = in_sizes[0];
  const int G = in_sizes[2];

  gfn_main<<<G, BLOCK, 0, stream>>>(scores, resid, stop_resid, validp, batch,
                                    (float*)d_out, E, G);
}